// Round 14
// baseline (151.586 us; speedup 1.0000x reference)
//
#include <hip/hip_runtime.h>
#include <hip/hip_bf16.h>

typedef unsigned short u16;
typedef unsigned int u32;
typedef __bf16 bf16x8 __attribute__((ext_vector_type(8)));
typedef float f32x4 __attribute__((ext_vector_type(4)));
typedef unsigned int u32x4 __attribute__((ext_vector_type(4)));
typedef unsigned int u32x2 __attribute__((ext_vector_type(2)));

#define NN 512
#define LL 40
#define DD 128
#define OO 256
#define KK 9
#define MHCL 34
#define TT 32
#define OC 32        // o-chunk per oc-iteration
#define OCPB 2       // oc iterations per block (grid 2048 for backfill depth)
#define KB 3         // k-batch size (3 batches of 3)
#define PSTR 136     // pept LDS row stride (u16)
#define MSTR 72      // mhcT LDS row stride (u16)
#define KSTR 136     // kern LDS row stride (u16)
#define KSLC (OC * KSTR)   // 4352 u16 = one kern k-slice
#define LPAD 64      // padded l-dim for MFMA K
#define WPADL 64     // padded l-dim in preconverted W

__device__ __forceinline__ u16 f2bf(float x) {
    unsigned int u = __builtin_bit_cast(unsigned int, x);
    u = (u + 0x7FFFu + ((u >> 16) & 1u)) >> 16;
    return (u16)u;
}
__device__ __forceinline__ u32 pk2(float a, float b) {
    __hip_bfloat162 h = __float22bfloat162_rn(make_float2(a, b)); // x = low half
    u32 r;
    __builtin_memcpy(&r, &h, 4);
    return r;
}
__device__ __forceinline__ bf16x8 lds_read8(const u16* p) {
    u32x4 r;
    __builtin_memcpy(&r, __builtin_assume_aligned(p, 16), 16);
    return __builtin_bit_cast(bf16x8, r);
}
__device__ __forceinline__ f32x4 mfma16(bf16x8 a, bf16x8 b, f32x4 c) {
    return __builtin_amdgcn_mfma_f32_16x16x32_bf16(a, b, c, 0, 0, 0);
}

// prologue: W fp32 [O][K][34] -> bf16 zero-padded [O][K][64] in ws
__global__ void w_convert(const float* __restrict__ wgt, u32* __restrict__ wp) {
    int i = blockIdx.x * 256 + threadIdx.x;        // 36864 u32
    if (i >= OO * KK * (WPADL / 2)) return;
    int o = i / (KK * (WPADL / 2));
    int r = i - o * (KK * (WPADL / 2));
    int k = r >> 5;
    int lp = (r & 31) << 1;
    const float* src = wgt + ((size_t)o * KK + k) * MHCL;
    float a = (lp     < MHCL) ? src[lp]     : 0.f;
    float b = (lp + 1 < MHCL) ? src[lp + 1] : 0.f;
    wp[i] = pk2(a, b);
}

template<bool PRE>
__global__ __launch_bounds__(256, 3)   // VGPR cap ~170: let the 12 W-fragments stay live
void iconv_kernel(const float* __restrict__ pept,
                  const float* __restrict__ mhc,
                  const float* __restrict__ wgt,
                  const u16* __restrict__ wp,
                  const float* __restrict__ bias,
                  float* __restrict__ out)
{
    // LDS: 10880 + 26112 = 36992 B -> 4 blocks/CU concurrent, grid depth 8 for backfill
    __shared__ __align__(16) u16 s_pept[LL * PSTR];
    __shared__ __align__(16) u16 s_uni[KB * KSLC];  // mhcT(18432B) -> kern[3](26112B) -> red f32[4][32][33](16896B)

    const int tid  = threadIdx.x;
    const int wv   = tid >> 6;
    const int lane = tid & 63;
    const int quad = lane >> 4;
    const int l16  = lane & 15;

    const int n    = blockIdx.x >> 2;   // 4 blocks per sample
    const int oc_q = blockIdx.x & 3;    // 2 of the 8 o-chunks each

    // ---- stage 0: staging, fp32 -> bf16 ----
    {
        const float* pg = pept + (size_t)n * LL * DD;
        #pragma unroll 1
        for (int i = tid; i < (LL * DD) / 4; i += 256) {
            int row = i >> 5, c4 = (i & 31) << 2;
            f32x4 v;
            __builtin_memcpy(&v, __builtin_assume_aligned(pg + row * DD + c4, 16), 16);
            u32x2 h = { pk2(v[0], v[1]), pk2(v[2], v[3]) };
            __builtin_memcpy(__builtin_assume_aligned(&s_pept[row * PSTR + c4], 8), &h, 8);
        }
        const float* mg = mhc + (size_t)n * MHCL * DD;
        #pragma unroll 1
        for (int i = tid; i < MHCL * DD; i += 256) {       // transpose-scatter
            int l = i >> 7, d = i & 127;
            s_uni[d * MSTR + l] = f2bf(mg[i]);
        }
        #pragma unroll 1
        for (int i = tid; i < DD * (LPAD - MHCL); i += 256) { // zero-pad l in [34,64)
            int d = i / 30, l = MHCL + (i - d * 30);
            s_uni[d * MSTR + l] = 0;
        }
    }
    __syncthreads();

    // ---- k-invariant mhc A-fragments into registers: wave owns d in [wv*32, wv*32+32) ----
    bf16x8 aF[2][2];   // [ntl][ki]; A[m=d][kdim=l]
    #pragma unroll
    for (int ntl = 0; ntl < 2; ++ntl) {
        const int d = (wv * 2 + ntl) * 16 + l16;
        aF[ntl][0] = lds_read8(&s_uni[d * MSTR + quad * 8]);
        aF[ntl][1] = lds_read8(&s_uni[d * MSTR + 32 + quad * 8]);
    }
    __syncthreads();   // mhcT dead -> kern[3] slices

    auto loadW = [&](int o_base, int k, bf16x8 wF[2][2]) {
        if (PRE) {
            #pragma unroll
            for (int mt = 0; mt < 2; ++mt) {
                const u16* wr = wp + ((size_t)(o_base + mt * 16 + l16) * KK + k) * WPADL;
                u32x4 r0, r1;
                __builtin_memcpy(&r0, __builtin_assume_aligned(wr + quad * 8, 16), 16);
                __builtin_memcpy(&r1, __builtin_assume_aligned(wr + 32 + quad * 8, 16), 16);
                wF[mt][0] = __builtin_bit_cast(bf16x8, r0);
                wF[mt][1] = __builtin_bit_cast(bf16x8, r1);
            }
        } else {
            #pragma unroll
            for (int mt = 0; mt < 2; ++mt) {
                const float* wrow = wgt + ((size_t)(o_base + mt * 16 + l16) * KK + k) * MHCL;
                float w8[8];
                __builtin_memcpy(w8, __builtin_assume_aligned(wrow + quad * 8, 8), 32);
                u16 h0[8];
                #pragma unroll
                for (int j = 0; j < 8; ++j) h0[j] = f2bf(w8[j]);
                __builtin_memcpy(&wF[mt][0], h0, 16);
                u16 h1[8] = {0,0,0,0,0,0,0,0};
                if (quad == 0) { h1[0] = f2bf(wrow[32]); h1[1] = f2bf(wrow[33]); }
                __builtin_memcpy(&wF[mt][1], h1, 16);
            }
        }
    };

    // stage1: wave computes kern rows (all o') for its d-columns [32*wv, +32) into slice
    auto stage1 = [&](const bf16x8 wF[2][2], u16* kslice) {
        #pragma unroll
        for (int ntl = 0; ntl < 2; ++ntl) {
            const int nt = wv * 2 + ntl;
            f32x4 c0 = {0.f,0.f,0.f,0.f}, c1 = c0;
            #pragma unroll
            for (int ki = 0; ki < 2; ++ki) {
                c0 = mfma16(aF[ntl][ki], wF[0][ki], c0);   // C[d_local][o' 0..15]
                c1 = mfma16(aF[ntl][ki], wF[1][ki], c1);   // C[d_local][o' 16..31]
            }
            u32x2 p0 = { pk2(fmaxf(c0[0], 0.f), fmaxf(c0[1], 0.f)),
                         pk2(fmaxf(c0[2], 0.f), fmaxf(c0[3], 0.f)) };
            u32x2 p1 = { pk2(fmaxf(c1[0], 0.f), fmaxf(c1[1], 0.f)),
                         pk2(fmaxf(c1[2], 0.f), fmaxf(c1[3], 0.f)) };
            __builtin_memcpy(__builtin_assume_aligned(&kslice[l16 * KSTR + nt * 16 + quad * 4], 8), &p0, 8);
            __builtin_memcpy(__builtin_assume_aligned(&kslice[(16 + l16) * KSTR + nt * 16 + quad * 4], 8), &p1, 8);
        }
    };

    const int off = wv * 32 + quad * 8;   // this wave's d-chunk column offset

    #pragma unroll 1
    for (int oci = 0; oci < OCPB; ++oci) {
        const int o_base = (oc_q * OCPB + oci) * OC;
        f32x4 acc00 = {0.f,0.f,0.f,0.f}, acc01 = acc00, acc10 = acc00, acc11 = acc00;

        // barrier-free, k-batched: phase1 fills 3 slices (12 indep loads, 24 indep MFMA),
        // phase2 drains 3 k of stage2. DS ops are wave-ordered; kern columns wave-private.
        #pragma unroll 1
        for (int kb = 0; kb < KK / KB; ++kb) {
            bf16x8 wF[KB][2][2];
            #pragma unroll
            for (int kk = 0; kk < KB; ++kk)
                loadW(o_base, kb * KB + kk, wF[kk]);
            #pragma unroll
            for (int kk = 0; kk < KB; ++kk)
                stage1(wF[kk], s_uni + kk * KSLC);
            #pragma unroll
            for (int kk = 0; kk < KB; ++kk) {
                const int k = kb * KB + kk;
                const u16* ks = s_uni + kk * KSLC;
                bf16x8 bk0 = lds_read8(&ks[l16 * KSTR + off]);
                bf16x8 bk1 = lds_read8(&ks[(16 + l16) * KSTR + off]);
                bf16x8 ap0 = lds_read8(&s_pept[(k + l16) * PSTR + off]);
                bf16x8 ap1 = lds_read8(&s_pept[(k + 16 + l16) * PSTR + off]);
                acc00 = mfma16(ap0, bk0, acc00);
                acc01 = mfma16(ap0, bk1, acc01);
                acc10 = mfma16(ap1, bk0, acc10);
                acc11 = mfma16(ap1, bk1, acc11);
            }
        }

        __syncthreads();   // all waves done with kern before red tramples the region
        float* red = (float*)s_uni;   // f32[4][32][33]
        {
            float* rw = red + wv * (TT * 33);
            #pragma unroll
            for (int r = 0; r < 4; ++r) {
                rw[(quad * 4 + r) * 33 + l16]           = acc00[r];
                rw[(quad * 4 + r) * 33 + 16 + l16]      = acc01[r];
                rw[(16 + quad * 4 + r) * 33 + l16]      = acc10[r];
                rw[(16 + quad * 4 + r) * 33 + 16 + l16] = acc11[r];
            }
        }
        __syncthreads();

        {
            const int o  = tid >> 3;         // 0..31
            const int t0 = (tid & 7) * 4;    // 0,4,...,28
            const float bv = bias[o_base + o];
            f32x4 res;
            #pragma unroll
            for (int j = 0; j < 4; ++j) {
                int idx = (t0 + j) * 33 + o;
                res[j] = red[idx] + red[TT * 33 + idx] + red[2 * TT * 33 + idx]
                       + red[3 * TT * 33 + idx] + bv;
            }
            float* op = out + ((size_t)n * OO + o_base + o) * TT + t0;
            __builtin_memcpy(__builtin_assume_aligned(op, 16), &res, 16);
        }
        __syncthreads();   // red reads drained before next oc's stage1 writes
    }
}

extern "C" void kernel_launch(void* const* d_in, const int* in_sizes, int n_in,
                              void* d_out, int out_size, void* d_ws, size_t ws_size,
                              hipStream_t stream) {
    const float* pept = (const float*)d_in[0];
    const float* mhc  = (const float*)d_in[1];
    const float* wgt  = (const float*)d_in[2];
    const float* bias = (const float*)d_in[3];
    float* out = (float*)d_out;

    const size_t w_bytes = (size_t)OO * KK * WPADL * sizeof(u16); // 294,912
    if (ws_size >= w_bytes) {
        w_convert<<<dim3((OO * KK * (WPADL / 2) + 255) / 256), dim3(256), 0, stream>>>(wgt, (u32*)d_ws);
        iconv_kernel<true><<<dim3(NN * 4), dim3(256), 0, stream>>>(pept, mhc, wgt, (const u16*)d_ws, bias, out);
    } else {
        iconv_kernel<false><<<dim3(NN * 4), dim3(256), 0, stream>>>(pept, mhc, wgt, nullptr, bias, out);
    }
}